// Round 8
// baseline (21352.608 us; speedup 1.0000x reference)
//
#include <hip/hip_runtime.h>
#include <math.h>

#define NB 256
#define NN 256
#define NK 128
#define ND 256
#define NH 512
#define NT 1024

// output layout (floats): x | f_out | u | p_u
#define OUT_X 0
#define OUT_F 65536
#define OUT_U 131072
#define OUT_P 196608

// per-batch ws: E slabs levels 1..8 (255*256 floats) + decision bits (256 ints)
#define EPB 65280
#define BPB (EPB + 256)

__host__ __device__ __forceinline__ int loff(int d) { return 256 - (1 << (9 - d)); }

// LDS scr layout (float4 units, scr4 total 8192 = 128 KB):
//   A slab:  scr4[0    .. 4095]  (<=32 rows x 128 f4)
//   parts:   scr4[1024 .. 3071]  (only ROWS<=8 passes; A then uses <=1024)
//   hid:     scr4[4096 .. 8191]  (<=32 rows x 128 f4)

#define FMA4(Av, W0, W1v, W2v, W3v, ACC)                      \
  ACC.x += Av.x * W0.x + Av.y * W1v.x + Av.z * W2v.x + Av.w * W3v.x; \
  ACC.y += Av.x * W0.y + Av.y * W1v.y + Av.z * W2v.y + Av.w * W3v.y; \
  ACC.z += Av.x * W0.z + Av.y * W1v.z + Av.z * W2v.z + Av.w * W3v.z; \
  ACC.w += Av.x * W0.w + Av.y * W1v.w + Av.z * W2v.w + Av.w * W3v.w;

#define LDWV(V0, V1, V2, V3, J)                               \
  {                                                           \
    const float* q_ = Wp + (size_t)(4 * (J)) * LDW;           \
    V0 = *(const float4*)q_;                                  \
    V1 = *(const float4*)(q_ + LDW);                          \
    V2 = *(const float4*)(q_ + 2 * LDW);                      \
    V3 = *(const float4*)(q_ + 3 * LDW);                      \
  }

// K-streaming engine: RPT rows x 4 cols, NC chunks of 4 k, 2-chunk-deep
// prefetch (8 float4 in flight). Ar = A base (row stride 512 floats).
template <int RPT, int NC, int LDW>
__device__ __forceinline__ void engine(const float* __restrict__ Wp,
                                       const float* __restrict__ Ar,
                                       float4* acc) {
  float4 a0, a1, a2, a3, b0, b1, b2, b3;
  LDWV(a0, a1, a2, a3, 0);
  LDWV(b0, b1, b2, b3, 1);
#pragma unroll 4
  for (int j = 0; j + 3 < NC; j += 2) {
    {
      float4 w0 = a0, w1 = a1, w2 = a2, w3 = a3;
      LDWV(a0, a1, a2, a3, j + 2);
#pragma unroll
      for (int r = 0; r < RPT; ++r) {
        const float4 av = *(const float4*)(Ar + r * 512 + 4 * j);
        FMA4(av, w0, w1, w2, w3, acc[r]);
      }
    }
    {
      float4 w0 = b0, w1 = b1, w2 = b2, w3 = b3;
      LDWV(b0, b1, b2, b3, j + 3);
#pragma unroll
      for (int r = 0; r < RPT; ++r) {
        const float4 av = *(const float4*)(Ar + r * 512 + 4 * (j + 1));
        FMA4(av, w0, w1, w2, w3, acc[r]);
      }
    }
  }
#pragma unroll
  for (int r = 0; r < RPT; ++r) {
    const float4 av = *(const float4*)(Ar + r * 512 + 4 * (NC - 2));
    FMA4(av, a0, a1, a2, a3, acc[r]);
  }
#pragma unroll
  for (int r = 0; r < RPT; ++r) {
    const float4 av = *(const float4*)(Ar + r * 512 + 4 * (NC - 1));
    FMA4(av, b0, b1, b2, b3, acc[r]);
  }
}

template <int K>
__device__ __forceinline__ constexpr int lg2() {
  return (K == 1) ? 0 : (K == 2) ? 1 : (K == 4) ? 2 : (K == 8) ? 3 : 4;
}

// ---------- GEMM1: hid[ROWS][512] = relu(A[ROWS][512] @ W1 + b1 (+emb)) ----------
template <int ROWS, int KS>
__device__ void g1t(float* __restrict__ scr, const int* __restrict__ bitR,
                    const float* __restrict__ embS, int tid,
                    const float* __restrict__ W1, const float* __restrict__ b1,
                    int isBn) {
  constexpr int LDW = NH;
  constexpr int RG = NT / (KS * 128);
  constexpr int RPT = ROWS / RG;
  constexpr int KN = 512 / KS;
  constexpr int NC = KN / 4;
  const int cq = tid & 127;
  const int ks = (tid >> 7) & (KS - 1);
  const int rg = tid >> (7 + lg2<KS>());
  const int c0 = cq * 4;
  const int r0 = rg * RPT;
  const float* Wp = W1 + (size_t)(ks * KN) * NH + c0;
  const float* Ar = scr + r0 * 512 + ks * KN;
  float4 acc[RPT];
#pragma unroll
  for (int r = 0; r < RPT; ++r) acc[r] = make_float4(0.f, 0.f, 0.f, 0.f);
  engine<RPT, NC, LDW>(Wp, Ar, acc);
  if (KS == 1) {
    const float4 bb = *(const float4*)(b1 + c0);
    float* hid = scr + 16384;
#pragma unroll
    for (int r = 0; r < RPT; ++r) {
      float4 v = acc[r];
      v.x += bb.x; v.y += bb.y; v.z += bb.z; v.w += bb.w;
      if (isBn) {
        const float4 e = *(const float4*)(embS + bitR[r0 + r] * 512 + c0);
        v.x += e.x; v.y += e.y; v.z += e.z; v.w += e.w;
      }
      v.x = fmaxf(v.x, 0.f); v.y = fmaxf(v.y, 0.f);
      v.z = fmaxf(v.z, 0.f); v.w = fmaxf(v.w, 0.f);
      *(float4*)(hid + (r0 + r) * 512 + c0) = v;
    }
  } else {
    float4* parts4 = (float4*)scr + 1024;
#pragma unroll
    for (int r = 0; r < RPT; ++r) parts4[(ks * ROWS + r0 + r) * 128 + cq] = acc[r];
  }
}

template <int ROWS, int KS>
__device__ void g1red(float* __restrict__ scr, const int* __restrict__ bitR,
                      const float* __restrict__ embS, int tid,
                      const float* __restrict__ b1, int isBn) {
  const float4* parts4 = (const float4*)scr + 1024;
  float* hid = scr + 16384;
  constexpr int E4 = ROWS * 128;
  for (int i = tid; i < E4; i += NT) {
    const int r = i >> 7, cq = i & 127;
    float4 s = *(const float4*)(b1 + cq * 4);
#pragma unroll
    for (int k = 0; k < KS; ++k) {
      const float4 p = parts4[(k * ROWS + r) * 128 + cq];
      s.x += p.x; s.y += p.y; s.z += p.z; s.w += p.w;
    }
    if (isBn) {
      const float4 e = *(const float4*)(embS + bitR[r] * 512 + cq * 4);
      s.x += e.x; s.y += e.y; s.z += e.z; s.w += e.w;
    }
    s.x = fmaxf(s.x, 0.f); s.y = fmaxf(s.y, 0.f);
    s.z = fmaxf(s.z, 0.f); s.w = fmaxf(s.w, 0.f);
    *(float4*)(hid + r * 512 + cq * 4) = s;
  }
}

// ---------- GEMM2: dst[ROWS][256] = hid[ROWS][512] @ W2 + b2 ----------
template <int ROWS, int KS>
__device__ void g2t(float* __restrict__ scr, int tid,
                    const float* __restrict__ W2, const float* __restrict__ b2,
                    float* __restrict__ dst) {
  constexpr int LDW = ND;
  constexpr int RG = NT / (KS * 64);
  constexpr int RPT = ROWS / RG;
  constexpr int KN = 512 / KS;
  constexpr int NC = KN / 4;
  const int cq = tid & 63;
  const int ks = (tid >> 6) & (KS - 1);
  const int rg = tid >> (6 + lg2<KS>());
  const int c0 = cq * 4;
  const int r0 = rg * RPT;
  const float* Wp = W2 + (size_t)(ks * KN) * ND + c0;
  const float* Ar = scr + 16384 + r0 * 512 + ks * KN;
  float4 acc[RPT];
#pragma unroll
  for (int r = 0; r < RPT; ++r) acc[r] = make_float4(0.f, 0.f, 0.f, 0.f);
  engine<RPT, NC, LDW>(Wp, Ar, acc);
  if (KS == 1) {
    const float4 bb = *(const float4*)(b2 + c0);
#pragma unroll
    for (int r = 0; r < RPT; ++r) {
      float4 v = acc[r];
      v.x += bb.x; v.y += bb.y; v.z += bb.z; v.w += bb.w;
      *(float4*)(dst + (size_t)(r0 + r) * ND + c0) = v;
    }
  } else {
    float4* parts4 = (float4*)scr + 1024;
#pragma unroll
    for (int r = 0; r < RPT; ++r) parts4[(ks * ROWS + r0 + r) * 64 + cq] = acc[r];
  }
}

template <int ROWS, int KS>
__device__ void g2red(float* __restrict__ scr, int tid,
                      const float* __restrict__ b2, float* __restrict__ dst) {
  const float4* parts4 = (const float4*)scr + 1024;
  constexpr int E4 = ROWS * 64;
  for (int i = tid; i < E4; i += NT) {
    const int r = i >> 6, cq = i & 63;
    float4 s = *(const float4*)(b2 + cq * 4);
#pragma unroll
    for (int k = 0; k < KS; ++k) {
      const float4 p = parts4[(k * ROWS + r) * 64 + cq];
      s.x += p.x; s.y += p.y; s.z += p.z; s.w += p.w;
    }
    *(float4*)(dst + (size_t)r * ND + cq * 4) = s;
  }
}

__global__ __launch_bounds__(NT, 4) void sc_stream(
    const int* __restrict__ info_bits, const float* __restrict__ rv,
    const int* __restrict__ info_set,
    const float* __restrict__ obs_emb, const float* __restrict__ label_emb,
    const float* __restrict__ cnW1, const float* __restrict__ cnb1,
    const float* __restrict__ cnW2, const float* __restrict__ cnb2,
    const float* __restrict__ bnW1, const float* __restrict__ bnb1,
    const float* __restrict__ bnW2, const float* __restrict__ bnb2,
    const float* __restrict__ llrW, const float* __restrict__ llrb,
    float* __restrict__ out, float* __restrict__ ws) {
  __shared__ float scr[32768];      // 128 KB
  __shared__ float embS[2 * 512];   // label_emb[bit] @ bnW1[512:768]
  __shared__ int fmap[256];
  __shared__ int curS[256], nxtS[256];
  __shared__ float red[8];
  __shared__ int bitR[32];

  const int tid = threadIdx.x, b = blockIdx.x;
  float* E = ws + (size_t)b * BPB;
  int* Lb = (int*)(E + EPB);
  const float* obs2 = obs_emb + 2 * ND;

  // ---- init: embC + fmap ----
  {
    const int bit = tid >> 9, col = tid & 511;
    float s = 0.f;
#pragma unroll 4
    for (int j = 0; j < ND; ++j)
      s += label_emb[bit * ND + j] * bnW1[(size_t)(NH + j) * NH + col];
    embS[bit * 512 + col] = s;
  }
  if (tid < 256) fmap[tid] = -1;
  __syncthreads();
  if (tid < NK) fmap[info_set[tid]] = tid;
  __syncthreads();

  auto pass = [&](int d, int isBn) {
    const int P = 1 << (7 - d);
    const float* Wa = isBn ? bnW1 : cnW1;
    const float* Ba = isBn ? bnb1 : cnb1;
    const float* Wb = isBn ? bnW2 : cnW2;
    const float* Bb = isBn ? bnb2 : cnb2;
    const float* Ed = (d == 0) ? nullptr : E + (size_t)loff(d) * ND;
    float* dstE = E + (size_t)loff(d + 1) * ND;
    const int CH = P >= 32 ? 32 : P;
    for (int p0 = 0; p0 < P; p0 += CH) {
      {  // stage A (contiguous copy: row r = [E[2(p0+r)] | E[2(p0+r)+1]])
        float4* A4 = (float4*)scr;
        const int n4 = CH * 128;
        if (Ed) {
          const float4* s4 = (const float4*)(Ed + (size_t)2 * p0 * ND);
          for (int i = tid; i < n4; i += NT) A4[i] = s4[i];
        } else {
          const float4* s4 = (const float4*)obs2;
          for (int i = tid; i < n4; i += NT) A4[i] = s4[i & 63];
        }
        if (isBn && tid < CH) bitR[tid] = Lb[loff(d + 1) + p0 + tid];
      }
      __syncthreads();
      float* dst = dstE + (size_t)p0 * ND;
      switch (CH) {
        case 32:
          g1t<32, 1>(scr, bitR, embS, tid, Wa, Ba, isBn); __syncthreads();
          g2t<32, 1>(scr, tid, Wb, Bb, dst); __syncthreads();
          break;
        case 16:
          g1t<16, 1>(scr, bitR, embS, tid, Wa, Ba, isBn); __syncthreads();
          g2t<16, 1>(scr, tid, Wb, Bb, dst); __syncthreads();
          break;
        case 8:
          g1t<8, 2>(scr, bitR, embS, tid, Wa, Ba, isBn); __syncthreads();
          g1red<8, 2>(scr, bitR, embS, tid, Ba, isBn); __syncthreads();
          g2t<8, 4>(scr, tid, Wb, Bb, dst); __syncthreads();
          g2red<8, 4>(scr, tid, Bb, dst); __syncthreads();
          break;
        case 4:
          g1t<4, 4>(scr, bitR, embS, tid, Wa, Ba, isBn); __syncthreads();
          g1red<4, 4>(scr, bitR, embS, tid, Ba, isBn); __syncthreads();
          g2t<4, 8>(scr, tid, Wb, Bb, dst); __syncthreads();
          g2red<4, 8>(scr, tid, Bb, dst); __syncthreads();
          break;
        case 2:
          g1t<2, 4>(scr, bitR, embS, tid, Wa, Ba, isBn); __syncthreads();
          g1red<2, 4>(scr, bitR, embS, tid, Ba, isBn); __syncthreads();
          g2t<2, 8>(scr, tid, Wb, Bb, dst); __syncthreads();
          g2red<2, 8>(scr, tid, Bb, dst); __syncthreads();
          break;
        default:
          g1t<1, 8>(scr, bitR, embS, tid, Wa, Ba, isBn); __syncthreads();
          g1red<1, 8>(scr, bitR, embS, tid, Ba, isBn); __syncthreads();
          g2t<1, 16>(scr, tid, Wb, Bb, dst); __syncthreads();
          g2red<1, 16>(scr, tid, Bb, dst); __syncthreads();
          break;
      }
    }
  };

  auto leaf = [&](int off) {
    const float* E8 = E + (size_t)loff(8) * ND;
    if (tid < 256) {
      const float ev = E8[tid];
      float v0 = ev * llrW[2 * tid];
      float v1 = ev * llrW[2 * tid + 1];
#pragma unroll
      for (int o = 32; o > 0; o >>= 1) {
        v0 += __shfl_down(v0, o);
        v1 += __shfl_down(v1, o);
      }
      if ((tid & 63) == 0) {
        red[tid >> 6] = v0;
        red[4 + (tid >> 6)] = v1;
      }
    }
    __syncthreads();
    if (tid == 0) {
      const float l0 = red[0] + red[1] + red[2] + red[3] + llrb[0];
      const float l1 = red[4] + red[5] + red[6] + red[7] + llrb[1];
      const float m = fmaxf(l0, l1);
      const float e0 = expf(l0 - m), e1 = expf(l1 - m);
      const float s = e0 + e1;
      const float p0 = e0 / s, p1 = e1 / s;
      const int hard = (rv[b * NN + off] > p0) ? 1 : 0;
      const int fidx = fmap[off];
      const int fval = (fidx >= 0) ? info_bits[b * NK + fidx] : 2;
      const int xb = (fval == 2) ? hard : fval;
      out[OUT_F + b * NN + off] = (fidx >= 0) ? 2.0f : (float)xb;
      out[OUT_U + b * NN + off] = (float)xb;
      out[OUT_P + (b * NN + off) * 2 + 0] = p0;
      out[OUT_P + (b * NN + off) * 2 + 1] = p1;
      curS[0] = xb;
    }
    __syncthreads();
    int* cur = curS;
    int* nxt = nxtS;
    int len = 1, lev = 8, idx = off;
    while (idx & 1) {
      if (tid < len) {
        const int c = cur[tid];
        nxt[2 * tid] = Lb[loff(lev) + tid] ^ c;
        nxt[2 * tid + 1] = c;
      }
      __syncthreads();
      int* t = cur; cur = nxt; nxt = t;
      len <<= 1; idx >>= 1; --lev;
    }
    if (lev > 0) {
      if (tid < len) Lb[loff(lev) + tid] = cur[tid];
    } else {
      if (tid < 256) out[OUT_X + b * NN + tid] = (float)cur[tid];
    }
    __syncthreads();
  };

  // ---- initial leftmost descent ----
  for (int d = 0; d < 8; ++d) pass(d, 0);
  // ---- sequential leaves ----
  for (int off = 0; off < NN; ++off) {
    leaf(off);
    if (off < NN - 1) {
      const int z = __ffs(off + 1) - 1;
      const int dbn = 7 - z;
      pass(dbn, 1);
      for (int d = dbn + 1; d < 8; ++d) pass(d, 0);
    }
  }
}

extern "C" void kernel_launch(void* const* d_in, const int* in_sizes, int n_in,
                              void* d_out, int out_size, void* d_ws, size_t ws_size,
                              hipStream_t stream) {
  const int*   info_bits = (const int*)d_in[0];
  const float* rv        = (const float*)d_in[1];
  const int*   info_set  = (const int*)d_in[2];
  const float* obs_emb   = (const float*)d_in[3];
  const float* label_emb = (const float*)d_in[4];
  const float* cnW1      = (const float*)d_in[5];
  const float* cnb1      = (const float*)d_in[6];
  const float* cnW2      = (const float*)d_in[7];
  const float* cnb2      = (const float*)d_in[8];
  const float* bnW1      = (const float*)d_in[9];
  const float* bnb1      = (const float*)d_in[10];
  const float* bnW2      = (const float*)d_in[11];
  const float* bnb2      = (const float*)d_in[12];
  const float* llrW      = (const float*)d_in[13];
  const float* llrb      = (const float*)d_in[14];

  float* out = (float*)d_out;
  float* ws  = (float*)d_ws;

  sc_stream<<<dim3(NB), dim3(NT), 0, stream>>>(
      info_bits, rv, info_set, obs_emb, label_emb,
      cnW1, cnb1, cnW2, cnb2, bnW1, bnb1, bnW2, bnb2,
      llrW, llrb, out, ws);
}

// Round 9
// 13347.417 us; speedup vs baseline: 1.5998x; 1.5998x over previous
//
#include <hip/hip_runtime.h>
#include <math.h>

#define NB 256
#define NN 256
#define NK 128
#define ND 256
#define NH 512
#define NT 1024

// output layout (floats): x | f_out | u | p_u
#define OUT_X 0
#define OUT_F 65536
#define OUT_U 131072
#define OUT_P 196608

// per-batch ws float offsets
#define EPB   65280            // E levels 1..8 (255*256)
#define SP6O  EPB              // bn6 spec: 4*256
#define S1O   (SP6O + 1024)    // 2*256
#define S2O   (S1O + 512)      // 4*256
#define S3O   (S2O + 1024)     // 8*256
#define LOFFI (S3O + 2048)     // 256 ints (decision-bit slabs)
#define BPB   (LOFFI + 256)

__host__ __device__ __forceinline__ int loff(int d) { return 256 - (1 << (9 - d)); }

// ---------------- GEMM1 k-split engine ----------------
// threads: 4 k-quarters (q=tid>>8) x 256 col-pairs. Zero weight redundancy:
// each thread reads W1[q*128 .. q*128+127][c0,c0+1] exactly once.
// A reads are wave-uniform (broadcast) ds_read_b128. Weights prefetched 1
// 4k-chunk ahead in named registers.
template <int PC>
__device__ void g1ks(const float* __restrict__ Abuf, float* __restrict__ part,
                     const int tid, const float* __restrict__ W1) {
  const int q = tid >> 8;
  const int c0 = (tid & 255) << 1;
  const float* Wp = W1 + (size_t)(q * 128) * NH + c0;
  const float* Ar = Abuf + q * 128;
  float a0[PC], a1[PC];
#pragma unroll
  for (int r = 0; r < PC; ++r) { a0[r] = 0.f; a1[r] = 0.f; }
  float2 n0 = *(const float2*)Wp;
  float2 n1 = *(const float2*)(Wp + NH);
  float2 n2 = *(const float2*)(Wp + 2 * NH);
  float2 n3 = *(const float2*)(Wp + 3 * NH);
#pragma unroll 2
  for (int kc = 0; kc < 124; kc += 4) {
    const float2 w0 = n0, w1 = n1, w2 = n2, w3 = n3;
    const float* Wn = Wp + (size_t)(kc + 4) * NH;
    n0 = *(const float2*)Wn;
    n1 = *(const float2*)(Wn + NH);
    n2 = *(const float2*)(Wn + 2 * NH);
    n3 = *(const float2*)(Wn + 3 * NH);
#pragma unroll
    for (int r = 0; r < PC; ++r) {
      const float4 av = *(const float4*)(Ar + r * 512 + kc);
      a0[r] += av.x * w0.x + av.y * w1.x + av.z * w2.x + av.w * w3.x;
      a1[r] += av.x * w0.y + av.y * w1.y + av.z * w2.y + av.w * w3.y;
    }
  }
#pragma unroll
  for (int r = 0; r < PC; ++r) {
    const float4 av = *(const float4*)(Ar + r * 512 + 124);
    a0[r] += av.x * n0.x + av.y * n1.x + av.z * n2.x + av.w * n3.x;
    a1[r] += av.x * n0.y + av.y * n1.y + av.z * n2.y + av.w * n3.y;
  }
#pragma unroll
  for (int r = 0; r < PC; ++r)
    *(float2*)&part[(q * PC + r) * 512 + c0] = make_float2(a0[r], a1[r]);
}

// reduce 4 quarters -> relu(+bias (+emb[bit])) -> hid rows [0,PC)
template <int PC>
__device__ void g1red(const float* __restrict__ part, float* __restrict__ hid,
                      const int tid, const float* __restrict__ b1,
                      const int isBn, const float* __restrict__ embS,
                      const int* __restrict__ bitR) {
  for (int i = tid; i < PC * 256; i += NT) {
    const int r = i >> 8, c0 = (i & 255) << 1;
    float2 s = *(const float2*)(b1 + c0);
#pragma unroll
    for (int qq = 0; qq < 4; ++qq) {
      const float2 p = *(const float2*)&part[(qq * PC + r) * 512 + c0];
      s.x += p.x; s.y += p.y;
    }
    if (isBn) {
      const float2 e = *(const float2*)&embS[bitR[r] * 512 + c0];
      s.x += e.x; s.y += e.y;
    }
    *(float2*)&hid[r * 512 + c0] = make_float2(fmaxf(s.x, 0.f), fmaxf(s.y, 0.f));
  }
}

// reduce + expand both bit-variants -> hid rows [base + 2r + b]
template <int R>
__device__ void g1redspec(const float* __restrict__ part, float* __restrict__ hid,
                          const int base, const int tid,
                          const float* __restrict__ b1,
                          const float* __restrict__ embS) {
  for (int i = tid; i < R * 256; i += NT) {
    const int r = i >> 8, c0 = (i & 255) << 1;
    float2 s = *(const float2*)(b1 + c0);
#pragma unroll
    for (int qq = 0; qq < 4; ++qq) {
      const float2 p = *(const float2*)&part[(qq * R + r) * 512 + c0];
      s.x += p.x; s.y += p.y;
    }
    const float2 e0 = *(const float2*)&embS[c0];
    const float2 e1 = *(const float2*)&embS[512 + c0];
    *(float2*)&hid[(base + 2 * r) * 512 + c0] =
        make_float2(fmaxf(s.x + e0.x, 0.f), fmaxf(s.y + e0.y, 0.f));
    *(float2*)&hid[(base + 2 * r + 1) * 512 + c0] =
        make_float2(fmaxf(s.x + e1.x, 0.f), fmaxf(s.y + e1.y, 0.f));
  }
}

// ---------------- GEMM2 k-split engine ----------------
// threads: 8 k-eighths (q=tid>>7) x 128 col-pairs; zero redundancy.
template <int RT>
__device__ void g2ks(const float* __restrict__ hid, const int hidBase,
                     float* __restrict__ part, const int tid,
                     const float* __restrict__ W2) {
  const int q = tid >> 7;
  const int c0 = (tid & 127) << 1;
  const float* Wp = W2 + (size_t)(q * 64) * ND + c0;
  const float* Hr = hid + hidBase * 512 + q * 64;
  float a0[RT], a1[RT];
#pragma unroll
  for (int r = 0; r < RT; ++r) { a0[r] = 0.f; a1[r] = 0.f; }
  float2 n0 = *(const float2*)Wp;
  float2 n1 = *(const float2*)(Wp + ND);
  float2 n2 = *(const float2*)(Wp + 2 * ND);
  float2 n3 = *(const float2*)(Wp + 3 * ND);
#pragma unroll 2
  for (int kc = 0; kc < 60; kc += 4) {
    const float2 w0 = n0, w1 = n1, w2 = n2, w3 = n3;
    const float* Wn = Wp + (size_t)(kc + 4) * ND;
    n0 = *(const float2*)Wn;
    n1 = *(const float2*)(Wn + ND);
    n2 = *(const float2*)(Wn + 2 * ND);
    n3 = *(const float2*)(Wn + 3 * ND);
#pragma unroll
    for (int r = 0; r < RT; ++r) {
      const float4 av = *(const float4*)(Hr + r * 512 + kc);
      a0[r] += av.x * w0.x + av.y * w1.x + av.z * w2.x + av.w * w3.x;
      a1[r] += av.x * w0.y + av.y * w1.y + av.z * w2.y + av.w * w3.y;
    }
  }
#pragma unroll
  for (int r = 0; r < RT; ++r) {
    const float4 av = *(const float4*)(Hr + r * 512 + 60);
    a0[r] += av.x * n0.x + av.y * n1.x + av.z * n2.x + av.w * n3.x;
    a1[r] += av.x * n0.y + av.y * n1.y + av.z * n2.y + av.w * n3.y;
  }
#pragma unroll
  for (int r = 0; r < RT; ++r)
    *(float2*)&part[(q * RT + r) * 256 + c0] = make_float2(a0[r], a1[r]);
}

template <int RT>
__device__ void g2red(const float* __restrict__ part, const int tid,
                      const float* __restrict__ b2,
                      float* const* __restrict__ rowDst) {
  for (int i = tid; i < RT * 128; i += NT) {
    const int r = i >> 7, c0 = (i & 127) << 1;
    float2 s = *(const float2*)(b2 + c0);
#pragma unroll
    for (int qq = 0; qq < 8; ++qq) {
      const float2 p = *(const float2*)&part[(qq * RT + r) * 256 + c0];
      s.x += p.x; s.y += p.y;
    }
    *(float2*)(rowDst[r] + c0) = s;
  }
}

__global__ __launch_bounds__(NT, 4) void sc_quad(
    const int* __restrict__ info_bits, const float* __restrict__ rv,
    const int* __restrict__ info_set,
    const float* __restrict__ obs_emb, const float* __restrict__ label_emb,
    const float* __restrict__ cnW1, const float* __restrict__ cnb1,
    const float* __restrict__ cnW2, const float* __restrict__ cnb2,
    const float* __restrict__ bnW1, const float* __restrict__ bnb1,
    const float* __restrict__ bnW2, const float* __restrict__ bnb2,
    const float* __restrict__ llrW, const float* __restrict__ llrb,
    float* __restrict__ out, float* __restrict__ ws) {
  __shared__ float A[4096];       // <=8 staged input rows
  __shared__ float part[20480];   // k-split partials (G1<=16384, G2<=20480)
  __shared__ float hid[8192];     // <=16 hidden rows
  __shared__ float embS[1024];    // label_emb[bit] @ bnW1[512:768]
  __shared__ float* rowDst[16];
  __shared__ int fmap[256];
  __shared__ int curS[256], nxtS[256];
  __shared__ float red[8];
  __shared__ int bitR[8];
  __shared__ int qbS[4];

  const int tid = threadIdx.x, b = blockIdx.x;
  float* wsb = ws + (size_t)b * BPB;
  float* E = wsb;
  float* sp6 = wsb + SP6O;
  float* S1 = wsb + S1O;
  float* S2 = wsb + S2O;
  float* S3 = wsb + S3O;
  int* Lb = (int*)(wsb + LOFFI);
  const float* obs2 = obs_emb + 2 * ND;

  // ---- init: embC + fmap ----
  {
    const int bit = tid >> 9, col = tid & 511;
    float s = 0.f;
#pragma unroll 4
    for (int j = 0; j < ND; ++j)
      s += label_emb[bit * ND + j] * bnW1[(size_t)(NH + j) * NH + col];
    embS[bit * 512 + col] = s;
  }
  if (tid < 256) fmap[tid] = -1;
  __syncthreads();
  if (tid < NK) fmap[info_set[tid]] = tid;
  __syncthreads();

  auto stageA = [&](const float* Ed, int p0, int R) {
    const int n4 = R * 128;
    float4* A4 = (float4*)A;
    if (Ed) {
      const float4* s4 = (const float4*)(Ed + (size_t)(2 * p0) * ND);
      for (int i = tid; i < n4; i += NT) A4[i] = s4[i];
    } else {
      const float4* o4 = (const float4*)obs2;
      for (int i = tid; i < n4; i += NT) A4[i] = o4[i & 63];
    }
  };

  auto plainPass = [&](int d, int isBn) {
    const int P = 1 << (7 - d);
    const float* W1 = isBn ? bnW1 : cnW1;
    const float* B1 = isBn ? bnb1 : cnb1;
    const float* W2 = isBn ? bnW2 : cnW2;
    const float* B2 = isBn ? bnb2 : cnb2;
    const float* Ed = (d == 0) ? nullptr : E + (size_t)loff(d) * ND;
    float* dstE = E + (size_t)loff(d + 1) * ND;
    const int PC = P >= 8 ? 8 : 4;  // d<=5 -> P>=4
    for (int p0 = 0; p0 < P; p0 += PC) {
      stageA(Ed, p0, PC);
      if (isBn && tid < PC) bitR[tid] = Lb[loff(d + 1) + p0 + tid];
      if (tid < PC) rowDst[tid] = dstE + (size_t)(p0 + tid) * ND;
      __syncthreads();
      if (PC == 8) {
        g1ks<8>(A, part, tid, W1); __syncthreads();
        g1red<8>(part, hid, tid, B1, isBn, embS, bitR); __syncthreads();
        g2ks<8>(hid, 0, part, tid, W2); __syncthreads();
        g2red<8>(part, tid, B2, rowDst); __syncthreads();
      } else {
        g1ks<4>(A, part, tid, W1); __syncthreads();
        g1red<4>(part, hid, tid, B1, isBn, embS, bitR); __syncthreads();
        g2ks<4>(hid, 0, part, tid, W2); __syncthreads();
        g2red<4>(part, tid, B2, rowDst); __syncthreads();
      }
    }
  };

  // depth-6 pair: cn6 (2 rows -> E7) + bn6 spec (2 rows x 2 bits -> sp6[0..3])
  auto pair6 = [&]() {
    stageA(E + (size_t)loff(6) * ND, 0, 2);
    if (tid < 2) rowDst[tid] = E + (size_t)(252 + tid) * ND;
    __syncthreads();
    g1ks<2>(A, part, tid, cnW1); __syncthreads();
    g1red<2>(part, hid, tid, cnb1, 0, embS, bitR); __syncthreads();
    g2ks<2>(hid, 0, part, tid, cnW2); __syncthreads();
    g2red<2>(part, tid, cnb2, rowDst); __syncthreads();
    g1ks<2>(A, part, tid, bnW1); __syncthreads();
    g1redspec<2>(part, hid, 2, tid, bnb1, embS); __syncthreads();
    g2ks<4>(hid, 2, part, tid, bnW2);
    if (tid < 4) rowDst[tid] = sp6 + (size_t)tid * ND;
    __syncthreads();
    g2red<4>(part, tid, bnb2, rowDst); __syncthreads();
  };

  // depth-7 combined: 5 A rows -> cn {E8, S2[0..3]} + bn-spec {S1[0..1], S3[0..7]}
  auto comb = [&]() {
    for (int i = tid; i < 5 * 128; i += NT) {
      const int r = i >> 7, k = (i & 127) << 2;
      const int h = k >> 8;
      const float* src;
      if (r == 0) src = E + (size_t)(252 + h) * ND;
      else {
        const int cc = r - 1;
        const int bit = (h == 0) ? (cc >> 1) : (cc & 1);
        src = sp6 + (size_t)(h * 2 + bit) * ND;
      }
      *(float4*)&A[r * 512 + k] = *(const float4*)&src[k & 255];
    }
    __syncthreads();
    g1ks<5>(A, part, tid, cnW1); __syncthreads();
    g1red<5>(part, hid, tid, cnb1, 0, embS, bitR); __syncthreads();
    g2ks<5>(hid, 0, part, tid, cnW2);
    if (tid < 5) rowDst[tid] = (tid == 0) ? (E + (size_t)254 * ND)
                                          : (S2 + (size_t)(tid - 1) * ND);
    __syncthreads();
    g2red<5>(part, tid, cnb2, rowDst); __syncthreads();
    g1ks<5>(A, part, tid, bnW1); __syncthreads();
    g1redspec<5>(part, hid, 5, tid, bnb1, embS); __syncthreads();
    g2ks<10>(hid, 5, part, tid, bnW2);
    if (tid < 10) rowDst[tid] = (tid < 2) ? (S1 + (size_t)tid * ND)
                                          : (S3 + (size_t)(tid - 2) * ND);
    __syncthreads();
    g2red<10>(part, tid, bnb2, rowDst); __syncthreads();
  };

  auto leaf = [&](int off) {
    const int ph = off & 3;
    const float* src;
    if (ph == 0) src = E + (size_t)254 * ND;
    else if (ph == 1) src = S1 + (size_t)qbS[0] * ND;
    else {
      const int cidx = 2 * (qbS[0] ^ qbS[1]) + qbS[1];
      src = (ph == 2) ? (S2 + (size_t)cidx * ND)
                      : (S3 + (size_t)(2 * cidx + qbS[2]) * ND);
    }
    if (tid < 256) {
      const float ev = src[tid];
      float v0 = ev * llrW[2 * tid];
      float v1 = ev * llrW[2 * tid + 1];
#pragma unroll
      for (int o = 32; o > 0; o >>= 1) {
        v0 += __shfl_down(v0, o);
        v1 += __shfl_down(v1, o);
      }
      if ((tid & 63) == 0) {
        red[tid >> 6] = v0;
        red[4 + (tid >> 6)] = v1;
      }
    }
    __syncthreads();
    if (tid == 0) {
      const float l0 = red[0] + red[1] + red[2] + red[3] + llrb[0];
      const float l1 = red[4] + red[5] + red[6] + red[7] + llrb[1];
      const float m = fmaxf(l0, l1);
      const float e0 = expf(l0 - m), e1 = expf(l1 - m);
      const float s = e0 + e1;
      const float p0 = e0 / s, p1 = e1 / s;
      const int hard = (rv[b * NN + off] > p0) ? 1 : 0;
      const int fidx = fmap[off];
      const int fval = (fidx >= 0) ? info_bits[b * NK + fidx] : 2;
      const int xb = (fval == 2) ? hard : fval;
      out[OUT_F + b * NN + off] = (fidx >= 0) ? 2.0f : (float)xb;
      out[OUT_U + b * NN + off] = (float)xb;
      out[OUT_P + (b * NN + off) * 2 + 0] = p0;
      out[OUT_P + (b * NN + off) * 2 + 1] = p1;
      curS[0] = xb;
      qbS[ph] = xb;
    }
    __syncthreads();
    int* cur = curS;
    int* nxt = nxtS;
    int len = 1, lev = 8, idx = off;
    while (idx & 1) {
      if (tid < len) {
        const int c = cur[tid];
        nxt[2 * tid] = Lb[loff(lev) + tid] ^ c;
        nxt[2 * tid + 1] = c;
      }
      __syncthreads();
      int* t = cur; cur = nxt; nxt = t;
      len <<= 1; idx >>= 1; --lev;
    }
    if (lev > 0) {
      if (tid < len) Lb[loff(lev) + tid] = cur[tid];
    } else {
      if (tid < 256) out[OUT_X + b * NN + tid] = (float)cur[tid];
    }
    __syncthreads();
  };

  // ---- initial descent ----
  for (int d = 0; d <= 5; ++d) plainPass(d, 0);
  pair6();
  comb();

  // ---- leaf loop ----
  for (int off = 0; off < NN; ++off) {
    leaf(off);
    if (off == NN - 1) break;
    const int t = off + 1;
    const int z = __ffs(t) - 1;
    if (z <= 1) continue;  // inside a quad: everything pre-speculated
    const int dbn = 7 - z;  // <= 5
    plainPass(dbn, 1);
    for (int d = dbn + 1; d <= 5; ++d) plainPass(d, 0);
    pair6();
    comb();
  }
}

extern "C" void kernel_launch(void* const* d_in, const int* in_sizes, int n_in,
                              void* d_out, int out_size, void* d_ws, size_t ws_size,
                              hipStream_t stream) {
  const int*   info_bits = (const int*)d_in[0];
  const float* rv        = (const float*)d_in[1];
  const int*   info_set  = (const int*)d_in[2];
  const float* obs_emb   = (const float*)d_in[3];
  const float* label_emb = (const float*)d_in[4];
  const float* cnW1      = (const float*)d_in[5];
  const float* cnb1      = (const float*)d_in[6];
  const float* cnW2      = (const float*)d_in[7];
  const float* cnb2      = (const float*)d_in[8];
  const float* bnW1      = (const float*)d_in[9];
  const float* bnb1      = (const float*)d_in[10];
  const float* bnW2      = (const float*)d_in[11];
  const float* bnb2      = (const float*)d_in[12];
  const float* llrW      = (const float*)d_in[13];
  const float* llrb      = (const float*)d_in[14];

  float* out = (float*)d_out;
  float* ws  = (float*)d_ws;

  sc_quad<<<dim3(NB), dim3(NT), 0, stream>>>(
      info_bits, rv, info_set, obs_emb, label_emb,
      cnW1, cnb1, cnW2, cnb2, bnW1, bnb1, bnW2, bnb2,
      llrW, llrb, out, ws);
}